// Round 6
// baseline (1322.775 us; speedup 1.0000x reference)
//
#include <hip/hip_runtime.h>
#include <hip/hip_bf16.h>

// GLA forward for MI355X. Inputs fp32, OUTPUT fp32 (reference is all-fp32;
// round-4/5 identical-absmax evidence => recurrence correct, output dtype was
// the bug). Pipeline:
//  1) gemm_k: q,k (QKT ws), v,g (bf16 ws) projections from fp32 x/W
//  2) gate_k: gk = log_sigmoid((x@Wgk1)@Wgk2 + b)/16  (GKT ws)
//  3) chunk_state_k: per-(b,h,chunk=64) local state sum S and decay D
//  4) scan_k: affine scan over chunks -> chunk-start states H_n (in place)
//  5) chunk_out_k: o = q*e^B @ H  +  causal-decayed intra attention @ V,
//     fused per-head LayerNorm + silu(g) gate -> OL (bf16, aliases G buffer)
//  6) gemm_k: out = OL @ Wo (fp32 to d_out)

typedef __hip_bfloat16 bf16;

#define DEV static __device__ __forceinline__

DEV float b2f(bf16 v) { return __bfloat162float(v); }
DEV bf16 f2b(float v) { return __float2bfloat16(v); }
DEV float bits2f(unsigned int u16) {
    union { unsigned int u; float f; } c; c.u = u16 << 16; return c.f;
}

DEV float ldf(const float* p) { return *p; }
DEV float ldf(const bf16* p) { return b2f(*p); }
DEV void stf(float* p, float v) { *p = v; }
DEV void stf(bf16* p, float v) { *p = f2b(v); }

// 4-element vector load, fp32 (16B) or bf16 (8B) source
DEV float4 ld4(const float* p) { return *(const float4*)p; }
DEV float4 ld4(const bf16* p) {
    const uint2 r = *(const uint2*)p;
    return make_float4(bits2f(r.x & 0xffffu), bits2f(r.x >> 16),
                       bits2f(r.y & 0xffffu), bits2f(r.y >> 16));
}

// ---------------------------------------------------------------------------
// Generic tiled GEMM: C[M,N] = scale * A[M,K] @ B[K,N] (AT/BT = float|bf16)
// BM=128, BN=64, BK=16; 256 threads, 8x4 per thread. fp32 accumulate.
// ---------------------------------------------------------------------------
template <typename AT, typename BT, typename OutT>
__global__ __launch_bounds__(256) void gemm_k(
    const AT* __restrict__ A, const BT* __restrict__ B,
    OutT* __restrict__ C, int M, int N, int K, float scale)
{
    __shared__ __align__(16) float As[16][132];  // [k][m] k-major, padded
    __shared__ __align__(16) float Bs[16][68];   // [k][n], padded
    const int bm = blockIdx.x * 128;
    const int bn = blockIdx.y * 64;
    const int tid = threadIdx.x;
    const int tx = tid & 15;
    const int ty = tid >> 4;

    float acc[8][4];
#pragma unroll
    for (int i = 0; i < 8; ++i)
#pragma unroll
        for (int j = 0; j < 4; ++j) acc[i][j] = 0.f;

    for (int k0 = 0; k0 < K; k0 += 16) {
        {   // stage A: 128 rows x 16 cols; 8/thread via 2x ld4
            const int r = tid >> 1;
            const int c8 = (tid & 1) * 8;
            const AT* ap = A + (size_t)(bm + r) * K + (k0 + c8);
            const float4 g0 = ld4(ap);
            const float4 g1 = ld4(ap + 4);
            As[c8 + 0][r] = g0.x; As[c8 + 1][r] = g0.y;
            As[c8 + 2][r] = g0.z; As[c8 + 3][r] = g0.w;
            As[c8 + 4][r] = g1.x; As[c8 + 5][r] = g1.y;
            As[c8 + 6][r] = g1.z; As[c8 + 7][r] = g1.w;
        }
        {   // stage B: 16 rows x 64 cols; 4/thread via ld4
            const int r = tid >> 4;
            const int c4 = (tid & 15) * 4;
            const float4 g = ld4(B + (size_t)(k0 + r) * N + (bn + c4));
            Bs[r][c4 + 0] = g.x; Bs[r][c4 + 1] = g.y;
            Bs[r][c4 + 2] = g.z; Bs[r][c4 + 3] = g.w;
        }
        __syncthreads();
#pragma unroll
        for (int k = 0; k < 16; ++k) {
            const float4* arow = (const float4*)(&As[k][ty * 8]);
            const float4 a0 = arow[0], a1 = arow[1];
            const float4 bb = *(const float4*)(&Bs[k][tx * 4]);
            const float av[8] = {a0.x, a0.y, a0.z, a0.w, a1.x, a1.y, a1.z, a1.w};
            const float bv[4] = {bb.x, bb.y, bb.z, bb.w};
#pragma unroll
            for (int i = 0; i < 8; ++i)
#pragma unroll
                for (int j = 0; j < 4; ++j)
                    acc[i][j] = fmaf(av[i], bv[j], acc[i][j]);
        }
        __syncthreads();
    }
#pragma unroll
    for (int i = 0; i < 8; ++i) {
        const size_t r = bm + ty * 8 + i;
#pragma unroll
        for (int j = 0; j < 4; ++j)
            stf(&C[r * N + (bn + tx * 4 + j)], acc[i][j] * scale);
    }
}

// ---------------------------------------------------------------------------
// gk = log_sigmoid((x @ Wgk1) @ Wgk2 + bgk2) / 16 ; one block per row
// ---------------------------------------------------------------------------
template <typename GKT>
__global__ __launch_bounds__(256) void gate_k(
    const float* __restrict__ x, const float* __restrict__ Wgk1,
    const float* __restrict__ Wgk2, const float* __restrict__ bgk2,
    GKT* __restrict__ GK)
{
    __shared__ float xs[512];
    __shared__ float part[16][17];
    __shared__ float tl[16];
    const int row = blockIdx.x;
    const int tid = threadIdx.x;
    const float* xp = x + (size_t)row * 512;
    xs[tid] = xp[tid];
    xs[tid + 256] = xp[tid + 256];
    __syncthreads();
    const int j = tid & 15, seg = tid >> 4;
    float p = 0.f;
#pragma unroll
    for (int i = 0; i < 32; ++i) {
        const int c = seg * 32 + i;
        p = fmaf(xs[c], Wgk1[c * 16 + j], p);
    }
    part[seg][j] = p;
    __syncthreads();
    if (tid < 16) {
        float s = 0.f;
#pragma unroll
        for (int sg = 0; sg < 16; ++sg) s += part[sg][tid];
        tl[tid] = s;
    }
    __syncthreads();
    float z = bgk2[tid];
#pragma unroll
    for (int r = 0; r < 16; ++r)
        z = fmaf(tl[r], Wgk2[r * 256 + tid], z);
    const float ls = fminf(z, 0.f) - log1pf(expf(-fabsf(z)));
    stf(&GK[(size_t)row * 256 + tid], ls * (1.f / 16.f));
}

// ---------------------------------------------------------------------------
// Per-chunk local state: S[k][v] = sum_t e^{B63[k]-Bt[k]} k_t[k] v_t[v],
// D[k] = e^{B63[k]}. Stored transposed: CS[blk][v*64+k]. blk = bh*256+chunk.
// ---------------------------------------------------------------------------
template <typename QKT, typename GKT, typename CST>
__global__ __launch_bounds__(256) void chunk_state_k(
    const QKT* __restrict__ Km, const bf16* __restrict__ Vm,
    const GKT* __restrict__ GKm, CST* __restrict__ CS,
    float* __restrict__ DD)
{
    __shared__ float gs[64][64];   // gk cumsum, then overwritten with k2
    __shared__ float d63[64];
    __shared__ __align__(16) float vs[64][128];
    const int blk = blockIdx.x;
    const int chunk = blk & 255;
    const int bh = blk >> 8;
    const int bi = bh >> 2, h = bh & 3;
    const int rowbase = bi * 16384 + chunk * 64;
    const int tid = threadIdx.x;

    for (int e = tid; e < 4096; e += 256) {
        const int t = e >> 6, k = e & 63;
        gs[t][k] = ldf(&GKm[(size_t)(rowbase + t) * 256 + h * 64 + k]);
    }
    __syncthreads();
    if (tid < 64) {
        float run = 0.f;
        for (int t = 0; t < 64; ++t) { run += gs[t][tid]; gs[t][tid] = run; }
        d63[tid] = run;
    }
    __syncthreads();
    for (int e = tid; e < 4096; e += 256) {
        const int t = e >> 6, k = e & 63;
        const float kv = ldf(&Km[(size_t)(rowbase + t) * 256 + h * 64 + k]);
        gs[t][k] = kv * expf(d63[k] - gs[t][k]);   // in-place: k2
    }
    for (int e = tid; e < 8192; e += 256) {
        const int t = e >> 7, v = e & 127;
        vs[t][v] = ldf(&Vm[(size_t)(rowbase + t) * 512 + h * 128 + v]);
    }
    if (tid < 64) DD[(size_t)blk * 64 + tid] = expf(d63[tid]);
    __syncthreads();

    const int kq = tid & 63, vq = tid >> 6;
    float acc[32];
#pragma unroll
    for (int j = 0; j < 32; ++j) acc[j] = 0.f;
    for (int t = 0; t < 64; ++t) {
        const float kc = gs[t][kq];
        const float4* vrow = (const float4*)(&vs[t][vq * 32]);
#pragma unroll
        for (int jj = 0; jj < 8; ++jj) {
            const float4 vv = vrow[jj];
            acc[jj * 4 + 0] = fmaf(kc, vv.x, acc[jj * 4 + 0]);
            acc[jj * 4 + 1] = fmaf(kc, vv.y, acc[jj * 4 + 1]);
            acc[jj * 4 + 2] = fmaf(kc, vv.z, acc[jj * 4 + 2]);
            acc[jj * 4 + 3] = fmaf(kc, vv.w, acc[jj * 4 + 3]);
        }
    }
    CST* out = CS + (size_t)blk * 8192;
#pragma unroll
    for (int j = 0; j < 32; ++j)
        stf(&out[(vq * 32 + j) * 64 + kq], acc[j]);
}

// ---------------------------------------------------------------------------
// Affine scan over chunks: slot n <- H_n (pre-chunk state), H_{n+1}=D_n H_n+S_n
// grid = 8 bh * 32 elem-slices; fully parallel across state elements.
// ---------------------------------------------------------------------------
template <typename CST>
__global__ __launch_bounds__(256) void scan_k(
    CST* __restrict__ CS, const float* __restrict__ DD)
{
    const int bh = blockIdx.x >> 5;
    const int slice = blockIdx.x & 31;
    const int tid = threadIdx.x;
    const int e = slice * 256 + tid;
    const int k = e & 63;
    float H = 0.f;
    CST* base = CS + (size_t)bh * 256 * 8192 + e;
    const float* dbase = DD + (size_t)bh * 256 * 64 + k;
#pragma unroll 4
    for (int n = 0; n < 256; ++n) {
        const float s = ldf(&base[(size_t)n * 8192]);
        const float d = dbase[(size_t)n * 64];
        const float nH = fmaf(d, H, s);
        stf(&base[(size_t)n * 8192], H);
        H = nH;
    }
}

// ---------------------------------------------------------------------------
// Per-chunk output + fused LayerNorm + silu gate.
//   A[t][i] = sum_k (q_t e^{Bt})[k] (k_i e^{-Bi})[k], i<=t
//   o_t = A @ V + (q_t e^{Bt}) @ H_n ; GO = LN(o)*silu(GO)  (bf16, in place)
// ---------------------------------------------------------------------------
template <typename QKT, typename GKT, typename CST>
__global__ __launch_bounds__(256) void chunk_out_k(
    const QKT* __restrict__ Qm, const QKT* __restrict__ Km,
    const bf16* __restrict__ Vm, const GKT* __restrict__ GKm,
    const CST* __restrict__ CS, bf16* GO)   // GO: read gate, write OL (same buf)
{
    __shared__ __align__(16) float smem[3 * 64 * 65 + 512];
    float (*gs)[65] = (float (*)[65])(smem);             // cumsum -> A
    float (*qs)[65] = (float (*)[65])(smem + 64 * 65);
    float (*ks)[65] = (float (*)[65])(smem + 2 * 64 * 65);
    float (*vs)[128] = (float (*)[128])(smem + 64 * 65); // overlays qs+ks
    float* redS = smem + 3 * 64 * 65;
    float* redQ = redS + 256;

    const int blk = blockIdx.x;
    const int chunk = blk & 255;
    const int bh = blk >> 8;
    const int bi = bh >> 2, h = bh & 3;
    const int rowbase = bi * 16384 + chunk * 64;
    const int tid = threadIdx.x;

    for (int e = tid; e < 4096; e += 256) {
        const int t = e >> 6, k = e & 63;
        gs[t][k] = ldf(&GKm[(size_t)(rowbase + t) * 256 + h * 64 + k]);
    }
    __syncthreads();
    if (tid < 64) {
        float run = 0.f;
        for (int t = 0; t < 64; ++t) { run += gs[t][tid]; gs[t][tid] = run; }
    }
    __syncthreads();
    for (int e = tid; e < 4096; e += 256) {
        const int t = e >> 6, k = e & 63;
        const float g = gs[t][k];
        const size_t idx = (size_t)(rowbase + t) * 256 + h * 64 + k;
        qs[t][k] = ldf(&Qm[idx]) * expf(g);
        ks[t][k] = ldf(&Km[idx]) * expf(-g);
    }
    __syncthreads();
    // A = (causal) qs @ ks^T, written into gs region
    {
        const int tq = tid >> 2, iq = tid & 3;
        float a[16];
#pragma unroll
        for (int j = 0; j < 16; ++j) a[j] = 0.f;
        for (int k = 0; k < 64; ++k) {
            const float qv = qs[tq][k];
#pragma unroll
            for (int j = 0; j < 16; ++j)
                a[j] = fmaf(qv, ks[iq * 16 + j][k], a[j]);
        }
#pragma unroll
        for (int j = 0; j < 16; ++j) {
            const int i = iq * 16 + j;
            gs[tq][i] = (i <= tq) ? a[j] : 0.f;
        }
    }
    // inter-chunk: acc += qs[t][:] . H[v][:]  (H rows contiguous)
    const int t = tid & 63, vq = tid >> 6;
    float acc[32];
#pragma unroll
    for (int j = 0; j < 32; ++j) acc[j] = 0.f;
    const CST* Hb = CS + (size_t)blk * 8192;
    for (int kb = 0; kb < 64; kb += 16) {
        float qreg[16];
#pragma unroll
        for (int kk = 0; kk < 16; ++kk) qreg[kk] = qs[t][kb + kk];
#pragma unroll
        for (int j = 0; j < 32; ++j) {
            const CST* hrow = Hb + (size_t)(vq * 32 + j) * 64 + kb;
            const float4 h0 = ld4(hrow + 0), h1 = ld4(hrow + 4);
            const float4 h2 = ld4(hrow + 8), h3 = ld4(hrow + 12);
            float s = acc[j];
            s = fmaf(qreg[0], h0.x, s);  s = fmaf(qreg[1], h0.y, s);
            s = fmaf(qreg[2], h0.z, s);  s = fmaf(qreg[3], h0.w, s);
            s = fmaf(qreg[4], h1.x, s);  s = fmaf(qreg[5], h1.y, s);
            s = fmaf(qreg[6], h1.z, s);  s = fmaf(qreg[7], h1.w, s);
            s = fmaf(qreg[8], h2.x, s);  s = fmaf(qreg[9], h2.y, s);
            s = fmaf(qreg[10], h2.z, s); s = fmaf(qreg[11], h2.w, s);
            s = fmaf(qreg[12], h3.x, s); s = fmaf(qreg[13], h3.y, s);
            s = fmaf(qreg[14], h3.z, s); s = fmaf(qreg[15], h3.w, s);
            acc[j] = s;
        }
    }
    __syncthreads();   // all done with qs/ks before overlaying with V
    for (int e = tid; e < 8192; e += 256) {
        const int tt = e >> 7, v = e & 127;
        vs[tt][v] = ldf(&Vm[(size_t)(rowbase + tt) * 512 + h * 128 + v]);
    }
    __syncthreads();
    // intra-chunk: acc += A[t][i] * V[i][v]
    for (int i = 0; i < 64; ++i) {
        const float av = gs[t][i];
        const float4* vrow = (const float4*)(&vs[i][vq * 32]);
#pragma unroll
        for (int jj = 0; jj < 8; ++jj) {
            const float4 vv = vrow[jj];
            acc[jj * 4 + 0] = fmaf(av, vv.x, acc[jj * 4 + 0]);
            acc[jj * 4 + 1] = fmaf(av, vv.y, acc[jj * 4 + 1]);
            acc[jj * 4 + 2] = fmaf(av, vv.z, acc[jj * 4 + 2]);
            acc[jj * 4 + 3] = fmaf(av, vv.w, acc[jj * 4 + 3]);
        }
    }
    // fused LayerNorm (over 128, split across 4 waves) + silu(g) gate
    float psum = 0.f, psq = 0.f;
#pragma unroll
    for (int j = 0; j < 32; ++j) { psum += acc[j]; psq = fmaf(acc[j], acc[j], psq); }
    redS[t * 4 + vq] = psum;
    redQ[t * 4 + vq] = psq;
    __syncthreads();
    const float s4 = redS[t * 4 + 0] + redS[t * 4 + 1] + redS[t * 4 + 2] + redS[t * 4 + 3];
    const float q4 = redQ[t * 4 + 0] + redQ[t * 4 + 1] + redQ[t * 4 + 2] + redQ[t * 4 + 3];
    const float mu = s4 * (1.f / 128.f);
    const float var = q4 * (1.f / 128.f) - mu * mu;
    const float rstd = rsqrtf(fmaxf(var, 0.f) + 1e-5f);
    const int row = rowbase + t;
    bf16* gop = GO + (size_t)row * 512 + h * 128 + vq * 32;
#pragma unroll
    for (int j = 0; j < 32; ++j) {
        const float gv = b2f(gop[j]);             // read gate
        const float sil = gv / (1.f + expf(-gv));
        gop[j] = f2b((acc[j] - mu) * rstd * sil); // overwrite with OL
    }
}

__global__ __launch_bounds__(256) void zero_k(float* out, int n) {
    const int i = blockIdx.x * 256 + threadIdx.x;
    if (i < n) out[i] = 0.f;
}

// ---------------------------------------------------------------------------
template <typename QKT, typename GKT, typename CST>
static void run_all(const float* x, const float* Wq, const float* Wk,
                    const float* Wv, const float* Wg, const float* Wgk1,
                    const float* Wgk2, const float* bgk2, const float* Wo,
                    float* out, char* ws, hipStream_t stream)
{
    const int M = 32768;  // B*S
    auto aln = [](size_t v) { return (v + 255) & ~(size_t)255; };
    char* cur = ws;
    QKT* Qb = (QKT*)cur;  cur += aln((size_t)M * 256 * sizeof(QKT));
    QKT* Kb = (QKT*)cur;  cur += aln((size_t)M * 256 * sizeof(QKT));
    bf16* Vb = (bf16*)cur;  cur += aln((size_t)M * 512 * 2);
    bf16* GOb = (bf16*)cur; cur += aln((size_t)M * 512 * 2);   // gate, then OL
    float* DDb = (float*)cur; cur += aln((size_t)2048 * 64 * 4);
    GKT* GKb = (GKT*)cur;   cur += aln((size_t)M * 256 * sizeof(GKT));
    CST* CSb = (CST*)cur;

    const dim3 blk(256);
    gemm_k<<<dim3(M / 128, 4), blk, 0, stream>>>(x, Wq, Qb, M, 256, 512, 0.125f);
    gemm_k<<<dim3(M / 128, 4), blk, 0, stream>>>(x, Wk, Kb, M, 256, 512, 1.f);
    gemm_k<<<dim3(M / 128, 8), blk, 0, stream>>>(x, Wv, Vb, M, 512, 512, 1.f);
    gemm_k<<<dim3(M / 128, 8), blk, 0, stream>>>(x, Wg, GOb, M, 512, 512, 1.f);
    gate_k<<<dim3(M), blk, 0, stream>>>(x, Wgk1, Wgk2, bgk2, GKb);
    chunk_state_k<<<dim3(2048), blk, 0, stream>>>(Kb, Vb, GKb, CSb, DDb);
    scan_k<<<dim3(256), blk, 0, stream>>>(CSb, DDb);
    chunk_out_k<<<dim3(2048), blk, 0, stream>>>(Qb, Kb, Vb, GKb, CSb, GOb);
    gemm_k<<<dim3(M / 128, 8), blk, 0, stream>>>(GOb, Wo, out, M, 512, 512, 1.f);
}

extern "C" void kernel_launch(void* const* d_in, const int* in_sizes, int n_in,
                              void* d_out, int out_size, void* d_ws, size_t ws_size,
                              hipStream_t stream)
{
    const float* x    = (const float*)d_in[0];
    const float* Wq   = (const float*)d_in[1];
    const float* Wk   = (const float*)d_in[2];
    const float* Wv   = (const float*)d_in[3];
    const float* Wg   = (const float*)d_in[4];
    const float* Wgk1 = (const float*)d_in[5];
    const float* Wgk2 = (const float*)d_in[6];
    const float* bgk2 = (const float*)d_in[7];
    const float* Wo   = (const float*)d_in[8];
    float* out = (float*)d_out;

    const size_t M = 32768;
    const size_t slack = 4096;
    // shared pieces: V (bf16) + GO (bf16) + DD
    const size_t base = M * 512 * 2 * 2 + 2048 * 64 * 4 + slack;
    const size_t qk_f = 2 * M * 256 * 4, qk_b = 2 * M * 256 * 2;
    const size_t gk_f = M * 256 * 4,     gk_b = M * 256 * 2;
    const size_t cs_f = (size_t)2048 * 8192 * 4, cs_b = (size_t)2048 * 8192 * 2;
    const size_t needA = base + qk_f + gk_f + cs_f;  // ~236 MB
    const size_t needB = base + qk_b + gk_f + cs_f;  // ~202 MB
    const size_t needC = base + qk_b + gk_b + cs_b;  // ~152 MB

    if (ws_size >= needA) {
        run_all<float, float, float>(x, Wq, Wk, Wv, Wg, Wgk1, Wgk2, bgk2, Wo,
                                     out, (char*)d_ws, stream);
    } else if (ws_size >= needB) {
        run_all<bf16, float, float>(x, Wq, Wk, Wv, Wg, Wgk1, Wgk2, bgk2, Wo,
                                    out, (char*)d_ws, stream);
    } else if (ws_size >= needC) {
        run_all<bf16, bf16, bf16>(x, Wq, Wk, Wv, Wg, Wgk1, Wgk2, bgk2, Wo,
                                  out, (char*)d_ws, stream);
    } else {
        // diagnostic: ws too small even for tier C -> deterministic zero output
        zero_k<<<dim3((out_size + 255) / 256), dim3(256), 0, stream>>>(out, out_size);
    }
}